// Round 7
// baseline (341.398 us; speedup 1.0000x reference)
//
#include <hip/hip_runtime.h>

// ---------------------------------------------------------------------------
// NeuralCellularAutomata fused pipeline for MI355X (gfx950) — v6
//   state[128,64,40,40] -> sobel perception(192) -> w1 GEMM(512) -> LN(sample)
//   -> ReLU -> w2 GEMM(64) -> mask*alive gate -> residual add
// LN stats via Gram trick; X1 never materialized. v6: barrier-free k4 main
// loop — each wave contracts GEMM2 over its OWN o-columns (all 64 s, 4
// s-frags in regs), Y staged in wave-PRIVATE LDS (same-wave write->read, no
// __syncthreads). Cross-wave acc2 reduction at the end (2-phase, 5 barriers
// total vs 17 in v5). GEMM1 mi-split (3+2) to cap VGPRs at 4 blocks/CU.
// ---------------------------------------------------------------------------

typedef unsigned short u16;
typedef unsigned int   u32;
typedef __attribute__((ext_vector_type(8))) u16    ushort8;
typedef __attribute__((ext_vector_type(4))) u16    u16x4;
typedef __attribute__((ext_vector_type(8))) __bf16 bf16x8;
typedef __attribute__((ext_vector_type(4))) float  f32x4;
typedef __attribute__((ext_vector_type(4))) u32    u32x4;

#define NB   128
#define NC   64
#define K1   192
#define NO   512
#define NHW  1600
#define LN_N 819200.0f

__device__ __forceinline__ u16 f2bf(float f) {
    union { float f; u32 u; } v; v.f = f;
    u32 u = v.u;
    u32 r = u + 0x7fffu + ((u >> 16) & 1u);   // round-nearest-even
    return (u16)(r >> 16);
}
__device__ __forceinline__ float bf2f(u16 h) {
    union { u32 u; float f; } v; v.u = ((u32)h) << 16; return v.f;
}
__device__ __forceinline__ float bfhi(u32 c) {
    union { u32 u; float f; } v; v.u = c & 0xffff0000u; return v.f;
}
__device__ __forceinline__ float bflo(u32 c) {
    union { u32 u; float f; } v; v.u = c << 16; return v.f;
}
__device__ __forceinline__ f32x4 mfma16(bf16x8 a, bf16x8 b, f32x4 c) {
    return __builtin_amdgcn_mfma_f32_16x16x32_bf16(a, b, c, 0, 0, 0);
}
__device__ __forceinline__ bf16x8 ldfrag(const u16* p) {
    return *(const bf16x8*)p;
}

// Shared perception helpers so k2_stats and k4_fused produce IDENTICAL bf16 P.
__device__ __forceinline__ void load_halo(const float* __restrict__ base, int h,
                                          int wq, float reg[3][12]) {
#pragma unroll
    for (int jj = 0; jj < 3; ++jj) {
        int hh = h + jj - 1;
        bool vh = (unsigned)hh < 40u;
        const float* rowp = base + hh * 40;
#pragma unroll
        for (int i = 0; i < 12; ++i) {
            int col = wq * 10 - 1 + i;
            reg[jj][i] = (vh && (unsigned)col < 40u) ? rowp[col] : 0.0f;
        }
    }
}
__device__ __forceinline__ void sobel_px(const float reg[3][12], int t,
                                         float& sx, float& sy, float& idn) {
    sx = (reg[0][t + 2] - reg[0][t]) + 2.0f * (reg[1][t + 2] - reg[1][t])
       + (reg[2][t + 2] - reg[2][t]);
    sy = (reg[2][t] + 2.0f * reg[2][t + 1] + reg[2][t + 2])
       - (reg[0][t] + 2.0f * reg[0][t + 1] + reg[0][t + 2]);
    idn = reg[1][t + 1];
}

// --- k0z: zero w2q panel (lanes 32..63 must be 0; ws is poisoned 0xAA) ------
__global__ __launch_bounds__(256) void k0_zero(u32* __restrict__ w2q32) {
    int i = blockIdx.x * 256 + threadIdx.x;
    if (i < 32768) w2q32[i] = 0u;
}

// --- k0a: pack w1 -> panel w1p + transposed w1T; w2 -> GEMM2 panel w2q ------
// w1p: element lane=(quad(k)<<4)|(o&15), j=k&7 at ((f*6+ks)*64+lane)*8+j.
// w2q: A-frag panel for k4 GEMM2 (K=16): for oc,sf,wid: lane=q*16+(s&15),
//   q<2 valid: value w2[s=sf*16+l15][o=oc*64+wid*16+q*8+j]; q>=2 stays zero.
__global__ __launch_bounds__(256) void k0_convert(const float* __restrict__ w1,
                                                  const float* __restrict__ w2,
                                                  u16* __restrict__ w1p,
                                                  u16* __restrict__ w1T,
                                                  u16* __restrict__ w2q,
                                                  float* __restrict__ stats) {
    int g = blockIdx.x * 256 + threadIdx.x;
    if (g < NO * K1) {
        u16 v = f2bf(w1[g]);
        int o = g / K1, k = g - o * K1;
        int f = o >> 4, ks = k >> 5;
        int lane = (((k >> 3) & 3) << 4) | (o & 15);
        w1p[(size_t)(((f * 6 + ks) * 64 + lane) * 8 + (k & 7))] = v;
        w1T[(size_t)k * NO + o] = v;
    } else if (g < NO * K1 + NC * NO) {
        int i = g - NO * K1;
        int s = i >> 9, o = i & 511;
        u16 v = f2bf(w2[i]);
        int oc = o >> 6, wid = (o >> 4) & 3, k = o & 15;
        int qq = k >> 3, j = o & 7;
        int lane = qq * 16 + (s & 15);
        int sf = s >> 4;
        w2q[((((size_t)(oc * 4 + sf) * 4 + wid) * 64 + lane) << 3) + j] = v;
    } else if (g < NO * K1 + NC * NO + 256) {
        stats[g - NO * K1 - NC * NO] = 0.0f;
    }
}

// --- k0l: pack ln params into C-fragment panel order ------------------------
// lnp[(((bx*8+oc)*4+wid)*5+mi)*256 + lane*4 + r] = (bf16(lnb)<<16)|bf16(lnw)
//   where p = bx*80+mi*16+(lane&15), o = oc*64+wid*16+(lane>>4)*4+r.
__global__ __launch_bounds__(256) void k0_lncomb(const float* __restrict__ lnw,
                                                 const float* __restrict__ lnb,
                                                 u32* __restrict__ lnp) {
    int g = blockIdx.x * 256 + threadIdx.x;   // over 1600*512
    int r = g & 3;
    int lane = (g >> 2) & 63;
    int rest = g >> 8;
    int mi = rest % 5;  rest /= 5;
    int wid = rest & 3; rest >>= 2;
    int oc = rest & 7;
    int bx = rest >> 3;
    int p = bx * 80 + mi * 16 + (lane & 15);
    int o = oc * 64 + wid * 16 + ((lane >> 4) << 2) + r;
    size_t gi = (size_t)o * NHW + p;
    lnp[g] = ((u32)f2bf(lnb[gi]) << 16) | f2bf(lnw[gi]);
}

// --- k0g: G = w1^T w1 via MFMA (blocks 0..35); colw1 (block 36) -------------
__global__ __launch_bounds__(256) void k0_gram(const u16* __restrict__ w1T,
                                               float* __restrict__ G,
                                               float* __restrict__ colw1) {
    const int blk = blockIdx.x;
    const int tid = threadIdx.x;
    const int lane = tid & 63, wid = tid >> 6;
    const int q = lane >> 4, l15 = lane & 15;
    if (blk < 36) {
        int bj = blk / 6, bk = blk - bj * 6;
        int j0 = bj * 32 + (wid & 1) * 16, k0 = bk * 32 + (wid >> 1) * 16;
        f32x4 acc = {0.f, 0.f, 0.f, 0.f};
#pragma unroll
        for (int ks = 0; ks < 16; ++ks) {
            bf16x8 a  = ldfrag(&w1T[(size_t)(j0 + l15) * NO + ks * 32 + q * 8]);
            bf16x8 bb = ldfrag(&w1T[(size_t)(k0 + l15) * NO + ks * 32 + q * 8]);
            acc = mfma16(a, bb, acc);
        }
#pragma unroll
        for (int r = 0; r < 4; ++r)
            G[(size_t)(j0 + q * 4 + r) * K1 + k0 + l15] = acc[r];
    } else if (tid < K1) {
        float s = 0.f;
        for (int i = 0; i < NO / 8; ++i) {
            ushort8 v = *(const ushort8*)&w1T[(size_t)tid * NO + i * 8];
#pragma unroll
            for (int j = 0; j < 8; ++j) s += bf2f(v[j]);
        }
        colw1[tid] = s;
    }
}

// --- k2: per-sample LN stats via Gram MFMA ----------------------------------
__global__ __launch_bounds__(256) void k2_stats(const float* __restrict__ state,
                                                const float* __restrict__ G,
                                                const float* __restrict__ colw1,
                                                float* __restrict__ stats) {
    const int b = blockIdx.x >> 2, quarter = blockIdx.x & 3;
    const int tid = threadIdx.x;
    const int lane = tid & 63, wid = tid >> 6;
    const int q = lane >> 4, l15 = lane & 15;
    const int j0 = (wid & 1) * 96, j1 = (wid >> 1) * 96, jo = wid * 48;

    __shared__ __align__(16) u16 Pt[208 * 104];   // 43264 B
    __shared__ float red[8];

    for (int i = tid; i < 208 * 104 / 2; i += 256) ((u32*)Pt)[i] = 0u;
    __syncthreads();
    if (tid < 80) Pt[192 * 104 + tid] = 0x3F80u;  // ones row (bf16 1.0)

    f32x4 acc[6][6], accO[3];
#pragma unroll
    for (int i = 0; i < 6; ++i)
#pragma unroll
        for (int j = 0; j < 6; ++j) { f32x4 z = {0.f,0.f,0.f,0.f}; acc[i][j] = z; }
#pragma unroll
    for (int j = 0; j < 3; ++j) { f32x4 z = {0.f,0.f,0.f,0.f}; accO[j] = z; }

    const int c = tid >> 2, wq = tid & 3;
    const float* base = state + ((size_t)b * NC + c) * NHW;

    for (int tile = 0; tile < 5; ++tile) {
        const int h0 = (quarter * 5 + tile) * 2;
        __syncthreads();                           // prev MFMA reads done
        for (int rr = 0; rr < 2; ++rr) {
            float reg[3][12];
            load_halo(base, h0 + rr, wq, reg);
#pragma unroll
            for (int t = 0; t < 10; ++t) {
                float sx, sy, idn; sobel_px(reg, t, sx, sy, idn);
                int px = rr * 40 + wq * 10 + t;
                Pt[(3 * c + 0) * 104 + px] = f2bf(sx);
                Pt[(3 * c + 1) * 104 + px] = f2bf(sy);
                Pt[(3 * c + 2) * 104 + px] = f2bf(idn);
            }
        }
        __syncthreads();
#pragma unroll
        for (int ks = 0; ks < 3; ++ks) {
            bf16x8 av[6], bv[6], ao, bo[3];
#pragma unroll
            for (int fi = 0; fi < 6; ++fi)
                av[fi] = ldfrag(&Pt[(j0 + fi * 16 + l15) * 104 + ks * 32 + q * 8]);
#pragma unroll
            for (int fj = 0; fj < 6; ++fj)
                bv[fj] = ldfrag(&Pt[(j1 + fj * 16 + l15) * 104 + ks * 32 + q * 8]);
            ao = ldfrag(&Pt[(192 + l15) * 104 + ks * 32 + q * 8]);
#pragma unroll
            for (int fj = 0; fj < 3; ++fj)
                bo[fj] = ldfrag(&Pt[(jo + fj * 16 + l15) * 104 + ks * 32 + q * 8]);
#pragma unroll
            for (int fi = 0; fi < 6; ++fi)
#pragma unroll
                for (int fj = 0; fj < 6; ++fj)
                    acc[fi][fj] = mfma16(av[fi], bv[fj], acc[fi][fj]);
#pragma unroll
            for (int fj = 0; fj < 3; ++fj)
                accO[fj] = mfma16(ao, bo[fj], accO[fj]);
        }
    }

    float ssq = 0.f;
#pragma unroll
    for (int fi = 0; fi < 6; ++fi)
#pragma unroll
        for (int fj = 0; fj < 6; ++fj) {
            f32x4 gv = *(const f32x4*)&G[(size_t)(j1 + fj * 16 + l15) * K1
                                         + j0 + fi * 16 + q * 4];
#pragma unroll
            for (int r = 0; r < 4; ++r) ssq += acc[fi][fj][r] * gv[r];
        }
    float sm = 0.f;
    if (q == 0) {
#pragma unroll
        for (int fj = 0; fj < 3; ++fj)
            sm += accO[fj][0] * colw1[jo + fj * 16 + l15];
    }
#pragma unroll
    for (int off = 32; off > 0; off >>= 1) {
        ssq += __shfl_down(ssq, off);
        sm  += __shfl_down(sm, off);
    }
    if (lane == 0) { red[wid] = ssq; red[4 + wid] = sm; }
    __syncthreads();
    if (tid == 0) {
        atomicAdd(&stats[b * 2],     red[4] + red[5] + red[6] + red[7]);
        atomicAdd(&stats[b * 2 + 1], red[0] + red[1] + red[2] + red[3]);
    }
}

// --- k3: finalize per-sample mu / rsigma ------------------------------------
__global__ void k3_finalize(const float* __restrict__ stats, float2* __restrict__ musig) {
    int t = threadIdx.x;
    if (t < NB) {
        float s = stats[2 * t], qq = stats[2 * t + 1];
        float inv = 1.0f / LN_N;
        float mu = s * inv;
        float var = qq * inv - mu * mu;
        float2 r; r.x = mu; r.y = rsqrtf(var + 1e-5f);
        musig[t] = r;
    }
}

// --- k4: fused, barrier-free main loop --------------------------------------
// Block: 80 px x one sample; 4 waves. Wave owns o = {oc*64 + wid*16 + 0..15}
// for oc=0..7 (128 o total). Per chunk: GEMM1 D[o][p] (mi-split 3+2), LN/ReLU
// transform -> wave-PRIVATE Ys (2560 B), GEMM2 (K=16, 4 s-frags = all 64 s)
// from own Ys — zero barriers. End: 2-phase cross-wave acc2 reduction in LDS.
__global__ __launch_bounds__(256, 4) void k4_fused(const float* __restrict__ state,
                                                   const u16* __restrict__ w1p,
                                                   const u16* __restrict__ w2q,
                                                   const u32* __restrict__ lnp,
                                                   const int* __restrict__ mask,
                                                   const float2* __restrict__ musig,
                                                   float* __restrict__ out) {
    const int bx = blockIdx.x;                    // 0..19
    const int b  = blockIdx.y;
    const int p0 = bx * 80, h0 = bx * 2;
    const int tid = threadIdx.x;
    const int lane = tid & 63, wid = tid >> 6;
    const int q = lane >> 4, l15 = lane & 15;

    __shared__ __align__(16) char smem[40960];    // Pt 30720 | Ys 4x2560
    u16* Pt  = (u16*)smem;
    u16* Ysw = (u16*)(smem + 30720) + wid * 1280; // private [p][16o] swizzled
    float* Rd = (float*)smem;                     // reduction slots (8 x 5120 B)

    const float2 ms = musig[b];
    const float mu = ms.x, rs = ms.y;
    const float murs = mu * rs;

    // perception -> Pt [p][192], group-of-8 XOR swizzle on 16B units
    {
        const int c = tid >> 2, wq = tid & 3;
        const float* base = state + ((size_t)b * NC + c) * NHW;
        for (int rr = 0; rr < 2; ++rr) {
            float reg[3][12];
            load_halo(base, h0 + rr, wq, reg);
#pragma unroll
            for (int t = 0; t < 10; ++t) {
                float sx, sy, idn; sobel_px(reg, t, sx, sy, idn);
                int px = rr * 40 + wq * 10 + t;
                int k = 3 * c;
#pragma unroll
                for (int i = 0; i < 3; ++i) {
                    int kk = k + i, u = kk >> 3;
                    int elem = px * 192 + (((u & 0x18) | ((u ^ px) & 7)) << 3) + (kk & 7);
                    Pt[elem] = f2bf(i == 0 ? sx : (i == 1 ? sy : idn));
                }
            }
        }
    }
    __syncthreads();                              // bar 1 (Pt ready)

    f32x4 acc2[4][5];
#pragma unroll
    for (int sf = 0; sf < 4; ++sf)
#pragma unroll
        for (int i = 0; i < 5; ++i) { f32x4 z = {0.f,0.f,0.f,0.f}; acc2[sf][i] = z; }

    const int swz = (((l15 >> 2) ^ l15) & 1);     // Ys bank swizzle bit (p-dep)

    for (int oc = 0; oc < 8; ++oc) {
        const u16* w1base = w1p + ((size_t)(oc * 4 + wid) * 6) * 512 + lane * 8;
        const u32* lbase = lnp + ((((size_t)bx * 8 + oc) * 4 + wid) * 5) * 256 + lane * 4;

        // ---- GEMM1 + transform, mi-group A (mi 0..2) ----
        {
            f32x4 acc1[3];
#pragma unroll
            for (int i = 0; i < 3; ++i) { f32x4 z = {0.f,0.f,0.f,0.f}; acc1[i] = z; }
#pragma unroll
            for (int ks = 0; ks < 6; ++ks) {
                bf16x8 a = ldfrag(w1base + (ks << 9));
#pragma unroll
                for (int mi = 0; mi < 3; ++mi) {
                    int r = mi * 16 + l15, u = ks * 4 + q;
                    bf16x8 bp = ldfrag(&Pt[r * 192 + (((u & 0x18) | ((u ^ r) & 7)) << 3)]);
                    acc1[mi] = mfma16(a, bp, acc1[mi]);
                }
            }
#pragma unroll
            for (int mi = 0; mi < 3; ++mi) {
                u32x4 lv = *(const u32x4*)(lbase + mi * 256);
                u16x4 yv;
#pragma unroll
                for (int r = 0; r < 4; ++r) {
                    u32 cc = lv[r];
                    float t = fmaf(acc1[mi][r], rs, -murs);
                    float y = fmaf(t, bflo(cc), bfhi(cc));
                    yv[r] = f2bf(fmaxf(y, 0.0f));
                }
                int p = mi * 16 + l15;
                *(u16x4*)&Ysw[p * 16 + (((q >> 1) ^ swz) << 3) + ((q & 1) << 2)] = yv;
            }
        }
        // ---- GEMM1 + transform, mi-group B (mi 3..4) ----
        {
            f32x4 acc1[2];
#pragma unroll
            for (int i = 0; i < 2; ++i) { f32x4 z = {0.f,0.f,0.f,0.f}; acc1[i] = z; }
#pragma unroll
            for (int ks = 0; ks < 6; ++ks) {
                bf16x8 a = ldfrag(w1base + (ks << 9));
#pragma unroll
                for (int mi = 0; mi < 2; ++mi) {
                    int r = (mi + 3) * 16 + l15, u = ks * 4 + q;
                    bf16x8 bp = ldfrag(&Pt[r * 192 + (((u & 0x18) | ((u ^ r) & 7)) << 3)]);
                    acc1[mi] = mfma16(a, bp, acc1[mi]);
                }
            }
#pragma unroll
            for (int mi = 0; mi < 2; ++mi) {
                u32x4 lv = *(const u32x4*)(lbase + (mi + 3) * 256);
                u16x4 yv;
#pragma unroll
                for (int r = 0; r < 4; ++r) {
                    u32 cc = lv[r];
                    float t = fmaf(acc1[mi][r], rs, -murs);
                    float y = fmaf(t, bflo(cc), bfhi(cc));
                    yv[r] = f2bf(fmaxf(y, 0.0f));
                }
                int p = (mi + 3) * 16 + l15;
                *(u16x4*)&Ysw[p * 16 + (((q >> 1) ^ swz) << 3) + ((q & 1) << 2)] = yv;
            }
        }
        // ---- GEMM2 (K=16): acc2[sf] += w2q-frag x own-Ys-frag; no barrier ----
        {
            bf16x8 aw0 = ldfrag(w2q + (((size_t)(oc * 4 + 0) * 4 + wid) << 9) + lane * 8);
            bf16x8 aw1 = ldfrag(w2q + (((size_t)(oc * 4 + 1) * 4 + wid) << 9) + lane * 8);
            bf16x8 aw2 = ldfrag(w2q + (((size_t)(oc * 4 + 2) * 4 + wid) << 9) + lane * 8);
            bf16x8 aw3 = ldfrag(w2q + (((size_t)(oc * 4 + 3) * 4 + wid) << 9) + lane * 8);
#pragma unroll
            for (int mi = 0; mi < 5; ++mi) {
                int p = mi * 16 + l15;
                bf16x8 by = ldfrag(&Ysw[p * 16 + ((((q & 1) ^ swz)) << 3)]);
                acc2[0][mi] = mfma16(aw0, by, acc2[0][mi]);
                acc2[1][mi] = mfma16(aw1, by, acc2[1][mi]);
                acc2[2][mi] = mfma16(aw2, by, acc2[2][mi]);
                acc2[3][mi] = mfma16(aw3, by, acc2[3][mi]);
            }
        }
    }

    // ---- cross-wave reduction of acc2 (2 phases, reuses Pt/Ys LDS) ----
    __syncthreads();                              // bar 2 (LDS free for reuse)
    // phase A: sfrags 0,1
#pragma unroll
    for (int sf = 0; sf < 2; ++sf) {
        if (wid != sf) {
#pragma unroll
            for (int mi = 0; mi < 5; ++mi)
                *(f32x4*)(Rd + (size_t)(sf * 4 + wid) * 1280 + mi * 256 + lane * 4)
                    = acc2[sf][mi];
        }
    }
    __syncthreads();                              // bar 3
#pragma unroll
    for (int sf = 0; sf < 2; ++sf) {
        if (wid == sf) {
#pragma unroll
            for (int w = 0; w < 4; ++w) {
                if (w == sf) continue;
#pragma unroll
                for (int mi = 0; mi < 5; ++mi) {
                    f32x4 v = *(const f32x4*)(Rd + (size_t)(sf * 4 + w) * 1280
                                              + mi * 256 + lane * 4);
#pragma unroll
                    for (int r = 0; r < 4; ++r) acc2[sf][mi][r] += v[r];
                }
            }
        }
    }
    __syncthreads();                              // bar 4
    // phase B: sfrags 2,3
#pragma unroll
    for (int sf = 2; sf < 4; ++sf) {
        if (wid != sf) {
#pragma unroll
            for (int mi = 0; mi < 5; ++mi)
                *(f32x4*)(Rd + (size_t)((sf - 2) * 4 + wid) * 1280 + mi * 256 + lane * 4)
                    = acc2[sf][mi];
        }
    }
    __syncthreads();                              // bar 5
#pragma unroll
    for (int sf = 2; sf < 4; ++sf) {
        if (wid == sf) {
#pragma unroll
            for (int w = 0; w < 4; ++w) {
                if (w == sf) continue;
#pragma unroll
                for (int mi = 0; mi < 5; ++mi) {
                    f32x4 v = *(const f32x4*)(Rd + (size_t)((sf - 2) * 4 + w) * 1280
                                              + mi * 256 + lane * 4);
#pragma unroll
                    for (int r = 0; r < 4; ++r) acc2[sf][mi][r] += v[r];
                }
            }
        }
    }

    // own s-frag -> accO (compile-time indexed)
    f32x4 accO[5];
#pragma unroll
    for (int sf = 0; sf < 4; ++sf)
        if (wid == sf) {
#pragma unroll
            for (int mi = 0; mi < 5; ++mi) accO[mi] = acc2[sf][mi];
        }

    // ---- gate + epilogue: out = state + gate * delta ----
    const float* st3 = state + ((size_t)b * NC + 3) * NHW;
#pragma unroll
    for (int mi = 0; mi < 5; ++mi) {
        int p = p0 + mi * 16 + l15;
        int h = p / 40, w = p - h * 40;
        float mx = -1e30f;
#pragma unroll
        for (int dh = -1; dh <= 1; ++dh) {
            int hh = h + dh;
            if ((unsigned)hh < 40u)
#pragma unroll
                for (int dw = -1; dw <= 1; ++dw) {
                    int wc = w + dw;
                    if ((unsigned)wc < 40u) mx = fmaxf(mx, st3[hh * 40 + wc]);
                }
        }
        float g = (mx > 0.1f && mask[p] != 0) ? 1.0f : 0.0f;
#pragma unroll
        for (int r = 0; r < 4; ++r) {
            int s = wid * 16 + q * 4 + r;
            size_t idx = ((size_t)b * NC + s) * NHW + p;
            out[idx] = state[idx] + g * accO[mi][r];
        }
    }
}

// ---------------------------------------------------------------------------
extern "C" void kernel_launch(void* const* d_in, const int* in_sizes, int n_in,
                              void* d_out, int out_size, void* d_ws, size_t ws_size,
                              hipStream_t stream) {
    const float* state = (const float*)d_in[0];
    const float* w1    = (const float*)d_in[1];
    const float* lnw   = (const float*)d_in[2];
    const float* lnb   = (const float*)d_in[3];
    const float* w2    = (const float*)d_in[4];
    const int*   mask  = (const int*)d_in[5];
    float* out = (float*)d_out;

    char* ws = (char*)d_ws;
    // workspace layout (total ~3.95 MB):
    u16*    w1p   = (u16*)(ws + 0ull);          //   196,608  GEMM1 A panel
    u16*    w2q   = (u16*)(ws + 196608ull);     //   131,072  GEMM2 A panel (K16)
    u32*    lnp   = (u32*)(ws + 327680ull);     // 3,276,800  panel (lnb|lnw)
    u16*    w1T   = (u16*)(ws + 3604480ull);    //   196,608  [k][o]
    float*  G     = (float*)(ws + 3801088ull);  //   147,456  w1^T w1
    float*  colw1 = (float*)(ws + 3948544ull);  //       768
    float*  stats = (float*)(ws + 3949312ull);  //     1,024
    float2* musig = (float2*)(ws + 3950336ull); //     1,024

    k0_zero    <<<128, 256, 0, stream>>>((u32*)w2q);
    k0_convert <<<513, 256, 0, stream>>>(w1, w2, w1p, w1T, w2q, stats);
    k0_lncomb  <<<3200, 256, 0, stream>>>(lnw, lnb, lnp);
    k0_gram    <<<37, 256, 0, stream>>>(w1T, G, colw1);
    k2_stats   <<<512, 256, 0, stream>>>(state, G, colw1, stats);
    k3_finalize<<<1, 128, 0, stream>>>(stats, musig);
    k4_fused   <<<dim3(20, 128), 256, 0, stream>>>(state, w1p, w2q, lnp,
                                                   mask, musig, out);
}